// Round 16
// baseline (280.647 us; speedup 1.0000x reference)
//
#include <hip/hip_runtime.h>

#define DEV __device__ __forceinline__
#define SB __builtin_amdgcn_sched_barrier(0)

typedef _Float16 f16;
typedef _Float16 f16x8 __attribute__((ext_vector_type(8)));
typedef _Float16 f16x4 __attribute__((ext_vector_type(4)));
typedef float f32x4 __attribute__((ext_vector_type(4)));
typedef unsigned int u32;

static constexpr int NB = 16;       // batch
static constexpr int NC = 256;      // channels
static constexpr int HW = 1024;     // h*w
static constexpr int NG = 32;       // groups
static constexpr int CPG = 8;       // channels per group
static constexpr int NH = 8;        // heads
static constexpr int HD = 64;       // head dim
static constexpr int INNER = 512;   // heads*head_dim
static constexpr int TD = 1024;     // time-embedding dim

DEV f32x4 mfma16(f16x8 a, f16x8 b, f32x4 c) {
    return __builtin_amdgcn_mfma_f32_16x16x32_f16(a, b, c, 0, 0, 0);
}

// pack two f32 -> one dword of two f16 (RTZ)
DEV u32 pk2(float a, float b) {
    auto c = __builtin_amdgcn_cvt_pkrtz(a, b);
    return __builtin_bit_cast(u32, c);
}
// raw v_exp_f32 (single instruction, no OCML edge handling)
DEV float fexp2(float x) { return __builtin_amdgcn_exp2f(x); }

// ---------------- fused prep: gn_stats | weight convert | embedding GEMM ----------------
__global__ void prep_k(const float* __restrict__ x, float* __restrict__ stats,
                       const float* __restrict__ in_w, const float* __restrict__ out_w,
                       f16* __restrict__ w_in, f16* __restrict__ w_out,
                       const float* __restrict__ e, const float* __restrict__ ew,
                       const float* __restrict__ eb, float* __restrict__ embS) {
    int bid = blockIdx.x;
    if (bid < NB * NG) {
        // ---- GroupNorm stats: per-(b,g) mean/rstd ----
        int bg = bid;
        const float4* p = reinterpret_cast<const float4*>(x) + (size_t)bg * (CPG * HW / 4);
        float s = 0.f, ss = 0.f;
        for (int i = threadIdx.x; i < CPG * HW / 4; i += 256) {
            float4 v = p[i];
            s  += v.x + v.y + v.z + v.w;
            ss += v.x * v.x + v.y * v.y + v.z * v.z + v.w * v.w;
        }
        #pragma unroll
        for (int o = 32; o > 0; o >>= 1) {
            s  += __shfl_xor(s, o);
            ss += __shfl_xor(ss, o);
        }
        __shared__ float rs[4], rss[4];
        int wid = threadIdx.x >> 6;
        if ((threadIdx.x & 63) == 0) { rs[wid] = s; rss[wid] = ss; }
        __syncthreads();
        if (threadIdx.x == 0) {
            s  = rs[0] + rs[1] + rs[2] + rs[3];
            ss = rss[0] + rss[1] + rss[2] + rss[3];
            const float inv_n = 1.f / (float)(CPG * HW);
            float mean = s * inv_n;
            float var  = ss * inv_n - mean * mean;
            stats[bg * 2]     = mean;
            stats[bg * 2 + 1] = rsqrtf(var + 1e-5f);
        }
    } else if (bid < NB * NG + 512) {
        // ---- fp32 -> f16 weight conversion ----
        int i = (bid - NB * NG) * 256 + threadIdx.x;   // float4 index
        const int N1 = 3 * INNER * NC / 4;             // 98304
        float4 v;
        f16* dst;
        if (i < N1) { v = reinterpret_cast<const float4*>(in_w)[i];       dst = w_in + (size_t)i * 4; }
        else        { v = reinterpret_cast<const float4*>(out_w)[i - N1]; dst = w_out + (size_t)(i - N1) * 4; }
        f16x4 h4 = {(f16)v.x, (f16)v.y, (f16)v.z, (f16)v.w};
        *reinterpret_cast<f16x4*>(dst) = h4;
    } else {
        // ---- embedding scale: embS[b][co] = embedding[b,:] . emb_w[co,:] + emb_b ----
        int u = bid - (NB * NG + 512);   // 0..1023
        int b = u >> 6;
        int co = ((u & 63) << 2) + (threadIdx.x >> 6);
        int lane = threadIdx.x & 63;
        const float4* ep = reinterpret_cast<const float4*>(e + (size_t)b * TD);
        const float4* wp = reinterpret_cast<const float4*>(ew + (size_t)co * TD);
        float s = 0.f;
        for (int t = lane; t < TD / 4; t += 64) {
            float4 a = ep[t], w = wp[t];
            s += a.x * w.x + a.y * w.y + a.z * w.z + a.w * w.w;
        }
        #pragma unroll
        for (int o = 32; o > 0; o >>= 1) s += __shfl_xor(s, o);
        if (lane == 0) embS[b * NC + co] = s + eb[co];
    }
}

// ---------------- GroupNorm apply + transpose -> xnT[b][m][c] (f16) ----------------
// 512 blocks (2/CU): block = 32 m-rows; 8 threads per m-row, 32 channels each.
__global__ void gn_apply_k(const float* __restrict__ x, const float* __restrict__ stats,
                           const float* __restrict__ nw, const float* __restrict__ nb,
                           f16* __restrict__ xnT) {
    int b = blockIdx.y;
    int m = blockIdx.x * 32 + (threadIdx.x & 31);
    int c0 = (threadIdx.x >> 5) * 32;
    const float* xb = x + (size_t)b * NC * HW + m;
    f16* op = xnT + ((size_t)b * HW + m) * NC + c0;
    #pragma unroll
    for (int cc = 0; cc < 32; cc += 8) {
        int cg = c0 + cc;
        float mean = stats[(b * NG + (cg >> 3)) * 2];
        float rstd = stats[(b * NG + (cg >> 3)) * 2 + 1];
        f16x8 h;
        #pragma unroll
        for (int j = 0; j < 8; ++j) {
            int c = cg + j;
            float v = xb[(size_t)c * HW];
            h[j] = (f16)(((v - mean) * rstd) * nw[c] + nb[c]);
        }
        *reinterpret_cast<f16x8*>(op + cc) = h;
    }
}

// ---------------- GEMM fragment loader (A/B panels, stride = K dim) ----------------
DEV void ld_ab4(const f16* __restrict__ A, const f16* __restrict__ Bp, int k0, int stride,
                f16x8 (&af)[4], f16x8 (&bf)[4]) {
    #pragma unroll
    for (int i = 0; i < 4; ++i)
        af[i] = *reinterpret_cast<const f16x8*>(A + (size_t)i * 16 * stride + k0);
    #pragma unroll
    for (int j = 0; j < 4; ++j)
        bf[j] = *reinterpret_cast<const f16x8*>(Bp + (size_t)j * 16 * stride + k0);
}
DEV void mm44(const f16x8 (&af)[4], const f16x8 (&bf)[4], f32x4 (&acc)[4][4]) {
    #pragma unroll
    for (int i = 0; i < 4; ++i)
        #pragma unroll
        for (int j = 0; j < 4; ++j)
            acc[i][j] = mfma16(af[i], bf[j], acc[i][j]);
}

// ---------------- QKV GEMM: qkv[o,m] = in_w[o,:] . xn[b,:,m], scatter to q/k/v ----------------
// K pre-scaled by 0.125*log2(e). Pinned double-buffered K-loop (r13 technique).
__global__ __launch_bounds__(256, 2) void gemm_qkv_k(
        const f16* __restrict__ wA, const f16* __restrict__ xnT,
        const float* __restrict__ bias,
        f16* __restrict__ qT, f16* __restrict__ kT, f16* __restrict__ vv) {
    int bid = blockIdx.x;                       // 1536 = 8 * 192
    int u = (bid & 7) * 192 + (bid >> 3);
    int o0 = (u % 12) * 128;
    int rr = u / 12;                            // 0..127
    int m0 = (rr & 7) * 128;
    int b  = rr >> 3;
    int wid  = threadIdx.x >> 6;
    int lane = threadIdx.x & 63;
    int wr = (wid >> 1) * 64, wc = (wid & 1) * 64;
    int lr = lane & 15, lg = lane >> 4;

    const f16* A  = wA  + (size_t)(o0 + wr + lr) * NC + lg * 8;
    const f16* Bp = xnT + ((size_t)b * HW + m0 + wc + lr) * NC + lg * 8;

    const f32x4 fzero = {0.f, 0.f, 0.f, 0.f};
    f32x4 acc[4][4];
    #pragma unroll
    for (int i = 0; i < 4; ++i)
        #pragma unroll
        for (int j = 0; j < 4; ++j) acc[i][j] = fzero;

    // K=256 in 8 steps of 32: 4 groups of 2, pinned 1-deep prefetch
    f16x8 afA[4], bfA[4], afB[4], bfB[4];
    ld_ab4(A, Bp, 0, NC, afA, bfA); SB;
    #pragma unroll 1
    for (int g = 0; g < 4; ++g) {
        int k0 = g * 64;
        ld_ab4(A, Bp, k0 + 32, NC, afB, bfB); SB;       // <= 224, always valid
        mm44(afA, bfA, acc); SB;
        if (g < 3) { ld_ab4(A, Bp, k0 + 64, NC, afA, bfA); } SB;
        mm44(afB, bfB, acc); SB;
    }

    const float SL = 0.18033688011112042f;  // 0.125 * log2(e)
    #pragma unroll
    for (int i = 0; i < 4; ++i) {
        int ob = o0 + wr + i * 16 + lg * 4;  // first of 4 consecutive output rows
        #pragma unroll
        for (int j = 0; j < 4; ++j) {
            int m = m0 + wc + j * 16 + lr;
            float v0 = acc[i][j][0] + bias[ob];
            float v1 = acc[i][j][1] + bias[ob + 1];
            float v2 = acc[i][j][2] + bias[ob + 2];
            float v3 = acc[i][j][3] + bias[ob + 3];
            if (ob < INNER) {                      // Q -> qT[bh][m][c]
                int h = ob >> 6, c = ob & 63;
                f16x4 pk = {(f16)v0, (f16)v1, (f16)v2, (f16)v3};
                *reinterpret_cast<f16x4*>(qT + (((size_t)(b * NH + h) * HW + m) * HD + c)) = pk;
            } else if (ob < 2 * INNER) {           // K -> kT[bh][n][c], pre-scaled
                int oo = ob - INNER;
                int h = oo >> 6, c = oo & 63;
                f16x4 pk = {(f16)(v0 * SL), (f16)(v1 * SL), (f16)(v2 * SL), (f16)(v3 * SL)};
                *reinterpret_cast<f16x4*>(kT + (((size_t)(b * NH + h) * HW + m) * HD + c)) = pk;
            } else {                               // V -> v[bh][c][n]
                int oo = ob - 2 * INNER;
                int h = oo >> 6, c = oo & 63;
                f16* vp = vv + ((size_t)(b * NH + h) * HD + c) * HW + m;
                vp[0]      = (f16)v0;
                vp[HW]     = (f16)v1;
                vp[2 * HW] = (f16)v2;
                vp[3 * HW] = (f16)v3;
            }
        }
    }
}

// ---------------- flash attention helpers ----------------
// Key-permuted K load: A(sc0) row i holds physical key 8*(i>>2)+(i&3),
// A(sc1) row i holds key 8*(i>>2)+4+(i&3). Softmax is key-permutation
// invariant; V is consumed in physical-key order, and with this permutation
// lane (lr,lg)'s S^T outputs are exactly keys 8*lg+{0..7} -- the PV B-fragment
// layout. P never leaves registers (no LDS).
DEV void load_kv(const f16* __restrict__ kp0, const f16* __restrict__ vp,
                 int n0, int lr, int lg, f16x8 (&kf)[2][2], f16x8 (&vf)[4]) {
    const f16* p0 = kp0 + (size_t)n0 * HD;
    kf[0][0] = *reinterpret_cast<const f16x8*>(p0);
    kf[0][1] = *reinterpret_cast<const f16x8*>(p0 + 32);
    kf[1][0] = *reinterpret_cast<const f16x8*>(p0 + 4 * HD);
    kf[1][1] = *reinterpret_cast<const f16x8*>(p0 + 4 * HD + 32);
    #pragma unroll
    for (int dt = 0; dt < 4; ++dt)
        vf[dt] = *reinterpret_cast<const f16x8*>(
            vp + (size_t)(dt * 16 + lr) * HW + n0 + lg * 8);
}

// One 32-key tile, chained per qt, all-register P (no LDS). Scores arrive in
// log2 units (K pre-scaled). Maps: round-1-verified 16x16x32 only.
template<int NQT>
DEV void attn_tile(const f16x8 (&kf)[2][2], const f16x8 (&vf)[4],
                   const f16x8 (&qf)[NQT][2],
                   f32x4 (&oa)[NQT][4], float (&mr)[NQT], float (&lsl)[NQT]) {
    const float THR = 11.0f;   // p <= 2^11, f16-safe
    const f32x4 fzero = {0.f, 0.f, 0.f, 0.f};
    #pragma unroll
    for (int qt = 0; qt < NQT; ++qt) {
        f32x4 sc0 = fzero, sc1 = fzero;
        __builtin_amdgcn_s_setprio(1);
        sc0 = mfma16(kf[0][0], qf[qt][0], sc0);
        sc0 = mfma16(kf[0][1], qf[qt][1], sc0);
        sc1 = mfma16(kf[1][0], qf[qt][0], sc1);
        sc1 = mfma16(kf[1][1], qf[qt][1], sc1);
        __builtin_amdgcn_s_setprio(0);

        // lane (lr,lg): sc0[r] = key 8lg+r, sc1[r] = key 8lg+4+r (log2 units)
        float m0 = fmaxf(fmaxf(sc0[0], sc0[1]), fmaxf(sc0[2], sc0[3]));
        float m1 = fmaxf(fmaxf(sc1[0], sc1[1]), fmaxf(sc1[2], sc1[3]));
        float pmax = fmaxf(m0, m1);
        if (__any(pmax - mr[qt] > THR)) {   // rare: first tile + big max jumps
            float pm = pmax;
            pm = fmaxf(pm, __shfl_xor(pm, 16));
            pm = fmaxf(pm, __shfl_xor(pm, 32));
            float mn = fmaxf(mr[qt], pm);
            float f = fexp2(mr[qt] - mn);   // first tile: exp2(-huge) = 0
            mr[qt] = mn;
            lsl[qt] *= f;
            #pragma unroll
            for (int dt = 0; dt < 4; ++dt)
                #pragma unroll
                for (int r = 0; r < 4; ++r) oa[qt][dt][r] *= f;
        }
        float p[8];
        #pragma unroll
        for (int r = 0; r < 4; ++r) p[r]     = fexp2(sc0[r] - mr[qt]);
        #pragma unroll
        for (int r = 0; r < 4; ++r) p[4 + r] = fexp2(sc1[r] - mr[qt]);
        lsl[qt] += ((p[0] + p[1]) + (p[2] + p[3])) + ((p[4] + p[5]) + (p[6] + p[7]));

        // PV B-fragment built fully in-register: element j = key 8lg+j
        union { u32 u[4]; f16x8 v; } pfu;
        pfu.u[0] = pk2(p[0], p[1]);
        pfu.u[1] = pk2(p[2], p[3]);
        pfu.u[2] = pk2(p[4], p[5]);
        pfu.u[3] = pk2(p[6], p[7]);

        __builtin_amdgcn_s_setprio(1);
        #pragma unroll
        for (int dt = 0; dt < 4; ++dt)
            oa[qt][dt] = mfma16(vf[dt], pfu.v, oa[qt][dt]);
        __builtin_amdgcn_s_setprio(0);
    }
}

// ---------------- flash attention: 8 waves/block, 32 q/wave, pinned depth-1, no LDS ----------------
// TLP config: 512 threads x 512 blocks = 4 waves/SIMD (2x the r15 residency).
// launch_bounds(512,4) caps VGPR at 128; qt=2 live set ~115 fits without spill.
// Pinned 2-buffer prefetch keeps loads one tile ahead; extra waves fill bubbles.
__global__ __launch_bounds__(512, 4) void attn_k(
        const f16* __restrict__ qT, const f16* __restrict__ kT, const f16* __restrict__ vv,
        f16* __restrict__ oT) {
    // XCD swizzle: 512 blocks, bid%8 -> XCD; give each XCD 16 whole bh's
    int u = ((blockIdx.x & 7) << 6) | (blockIdx.x >> 3);
    int bh = u >> 2;               // b*NH + h
    int mt = u & 3;
    int b = bh >> 3, h = bh & 7;
    int wid = threadIdx.x >> 6;    // 0..7
    int lane = threadIdx.x & 63;
    int lr = lane & 15, lg = lane >> 4;
    int mw = mt * 256 + wid * 32;  // 8 waves x 32 q = 256 q per block

    const f16* qp = qT + (size_t)bh * HW * HD;
    // permuted K base: lane reads physical key row 8*(lr>>2)+(lr&3) (+4 for sc1)
    const f16* kp0 = kT + (size_t)bh * HW * HD
                   + (size_t)(8 * (lr >> 2) + (lr & 3)) * HD + lg * 8;
    const f16* vp = vv + (size_t)bh * HD * HW;

    // Q fragments (B-operand): col=q=lr, k = d = ks2*32 + lg*8 + j
    f16x8 qf[2][2];
    #pragma unroll
    for (int qt = 0; qt < 2; ++qt)
        #pragma unroll
        for (int ks2 = 0; ks2 < 2; ++ks2)
            qf[qt][ks2] = *reinterpret_cast<const f16x8*>(
                qp + (size_t)(mw + qt * 16 + lr) * HD + ks2 * 32 + lg * 8);

    const f32x4 fzero = {0.f, 0.f, 0.f, 0.f};
    f32x4 oa[2][4];                // [qt][dt] : O^T[d=dt*16+lg*4+r][q=qt*16+lr]
    #pragma unroll
    for (int qt = 0; qt < 2; ++qt)
        #pragma unroll
        for (int dt = 0; dt < 4; ++dt) oa[qt][dt] = fzero;
    float mr[2]  = {-1e30f, -1e30f};
    float lsl[2] = {0.f, 0.f};     // per-lane partial denominators

    // 2-buffer rotation, 1 tile in flight, issue order PINNED.
    // 32 tiles = 16 groups of 2. Max load index = t31. No OOB.
    f16x8 kfA[2][2], vfA[4], kfB[2][2], vfB[4];
    load_kv(kp0, vp, 0, lr, lg, kfA, vfA); SB;
    #pragma unroll 1
    for (int g = 0; g < 16; ++g) {
        int n0 = g * 64;
        load_kv(kp0, vp, n0 + 32, lr, lg, kfB, vfB); SB;
        attn_tile<2>(kfA, vfA, qf, oa, mr, lsl); SB;
        if (g < 15) { load_kv(kp0, vp, n0 + 64, lr, lg, kfA, vfA); } SB;
        attn_tile<2>(kfB, vfB, qf, oa, mr, lsl); SB;
    }

    // finalize: reduce per-lane partials across the 4 lg lanes per query
    #pragma unroll
    for (int qt = 0; qt < 2; ++qt) {
        float t = lsl[qt];
        t += __shfl_xor(t, 16);
        t += __shfl_xor(t, 32);
        float inv = 1.f / t;
        int m = mw + qt * 16 + lr;
        f16* op = oT + ((size_t)b * HW + m) * INNER + h * HD;
        #pragma unroll
        for (int dt = 0; dt < 4; ++dt) {
            f16x4 o4;
            #pragma unroll
            for (int r = 0; r < 4; ++r) o4[r] = (f16)(oa[qt][dt][r] * inv);
            *reinterpret_cast<f16x4*>(op + dt * 16 + lg * 4) = o4;
        }
    }
}

// ---------------- out projection + bias + emb-scale + residual ----------------
// 64x128 tiles -> 512 blocks (2/CU), XCD-chunk swizzle, pinned dbuf K-loop.
__global__ __launch_bounds__(256) void gemm_out_k(
        const f16* __restrict__ wA, const f16* __restrict__ oT,
        const float* __restrict__ bias, const float* __restrict__ embS,
        const float* __restrict__ x, float* __restrict__ out) {
    int bid = blockIdx.x;                       // 512 = 8 * 64
    int u = (bid & 7) * 64 + (bid >> 3);
    int o0 = (u & 3) * 64;
    int rr = u >> 2;                            // 0..127
    int m0 = (rr & 7) * 128;
    int b  = rr >> 3;
    int wid  = threadIdx.x >> 6;
    int lane = threadIdx.x & 63;
    int wr = (wid >> 1) * 32, wc = (wid & 1) * 64;
    int lr = lane & 15, lg = lane >> 4;

    const f16* A  = wA + (size_t)(o0 + wr + lr) * INNER + lg * 8;
    const f16* Bp = oT + ((size_t)b * HW + m0 + wc + lr) * INNER + lg * 8;

    const f32x4 fzero = {0.f, 0.f, 0.f, 0.f};
    f32x4 acc[2][4];
    #pragma unroll
    for (int i = 0; i < 2; ++i)
        #pragma unroll
        for (int j = 0; j < 4; ++j) acc[i][j] = fzero;

    // K=512 in 16 steps of 32: 8 groups of 2, pinned 1-deep prefetch
    f16x8 afA[2], bfA[4], afB[2], bfB[4];
    auto ld = [&](int k0, f16x8 (&af)[2], f16x8 (&bf)[4]) {
        #pragma unroll
        for (int i = 0; i < 2; ++i)
            af[i] = *reinterpret_cast<const f16x8*>(A + (size_t)i * 16 * INNER + k0);
        #pragma unroll
        for (int j = 0; j < 4; ++j)
            bf[j] = *reinterpret_cast<const f16x8*>(Bp + (size_t)j * 16 * INNER + k0);
    };
    auto mm = [&](const f16x8 (&af)[2], const f16x8 (&bf)[4]) {
        #pragma unroll
        for (int i = 0; i < 2; ++i)
            #pragma unroll
            for (int j = 0; j < 4; ++j)
                acc[i][j] = mfma16(af[i], bf[j], acc[i][j]);
    };
    ld(0, afA, bfA); SB;
    #pragma unroll 1
    for (int g = 0; g < 8; ++g) {
        int k0 = g * 64;
        ld(k0 + 32, afB, bfB); SB;                    // <= 480, always valid
        mm(afA, bfA); SB;
        if (g < 7) { ld(k0 + 64, afA, bfA); } SB;
        mm(afB, bfB); SB;
    }

    #pragma unroll
    for (int i = 0; i < 2; ++i) {
        int ob = o0 + wr + i * 16 + lg * 4;
        #pragma unroll
        for (int j = 0; j < 4; ++j) {
            int m = m0 + wc + j * 16 + lr;
            #pragma unroll
            for (int r = 0; r < 4; ++r) {
                int o = ob + r;
                size_t idx = ((size_t)b * NC + o) * HW + m;
                out[idx] = (acc[i][j][r] + bias[o]) * embS[b * NC + o] + x[idx];
            }
        }
    }
}

extern "C" void kernel_launch(void* const* d_in, const int* in_sizes, int n_in,
                              void* d_out, int out_size, void* d_ws, size_t ws_size,
                              hipStream_t stream) {
    const float* x     = (const float*)d_in[0];
    const float* emb   = (const float*)d_in[1];
    const float* nw    = (const float*)d_in[2];
    const float* nbi   = (const float*)d_in[3];
    const float* in_w  = (const float*)d_in[4];
    const float* in_b  = (const float*)d_in[5];
    const float* out_w = (const float*)d_in[6];
    const float* out_b = (const float*)d_in[7];
    const float* emb_w = (const float*)d_in[8];
    const float* emb_b = (const float*)d_in[9];

    char* p = (char*)d_ws;
    f16* xnT   = (f16*)p;   p += (size_t)NB * HW * NC * 2;        // 8 MB
    f16* w_in  = (f16*)p;   p += (size_t)3 * INNER * NC * 2;      // 768 KB
    f16* w_out = (f16*)p;   p += (size_t)NC * INNER * 2;          // 256 KB
    float* stats = (float*)p; p += (size_t)NB * NG * 2 * 4;       // 4 KB
    float* embS  = (float*)p; p += (size_t)NB * NC * 4;           // 16 KB
    f16* qT = (f16*)p;      p += (size_t)NB * NH * HW * HD * 2;   // 16 MB
    f16* kT = (f16*)p;      p += (size_t)NB * NH * HW * HD * 2;   // 16 MB
    f16* vv = (f16*)p;      p += (size_t)NB * NH * HW * HD * 2;   // 16 MB
    f16* oT = (f16*)p;                                            // 16 MB

    prep_k<<<NB * NG + 512 + 1024, 256, 0, stream>>>(x, stats, in_w, out_w, w_in, w_out,
                                                     emb, emb_w, emb_b, embS);
    gn_apply_k<<<dim3(HW / 32, NB), 256, 0, stream>>>(x, stats, nw, nbi, xnT);
    gemm_qkv_k<<<1536, 256, 0, stream>>>(w_in, xnT, in_b, qT, kT, vv);
    attn_k<<<512, 512, 0, stream>>>(qT, kT, vv, oT);
    gemm_out_k<<<512, 256, 0, stream>>>(w_out, oT, out_b, embS, x, (float*)d_out);
}

// Round 17
// 158.497 us; speedup vs baseline: 1.7707x; 1.7707x over previous
//
#include <hip/hip_runtime.h>

#define DEV __device__ __forceinline__
#define SB __builtin_amdgcn_sched_barrier(0)

typedef _Float16 f16;
typedef _Float16 f16x8 __attribute__((ext_vector_type(8)));
typedef _Float16 f16x4 __attribute__((ext_vector_type(4)));
typedef float f32x4 __attribute__((ext_vector_type(4)));
typedef unsigned int u32;

static constexpr int NB = 16;       // batch
static constexpr int NC = 256;      // channels
static constexpr int HW = 1024;     // h*w
static constexpr int NG = 32;       // groups
static constexpr int CPG = 8;       // channels per group
static constexpr int NH = 8;        // heads
static constexpr int HD = 64;       // head dim
static constexpr int INNER = 512;   // heads*head_dim
static constexpr int TD = 1024;     // time-embedding dim

DEV f32x4 mfma16(f16x8 a, f16x8 b, f32x4 c) {
    return __builtin_amdgcn_mfma_f32_16x16x32_f16(a, b, c, 0, 0, 0);
}

// pack two f32 -> one dword of two f16 (RTZ)
DEV u32 pk2(float a, float b) {
    auto c = __builtin_amdgcn_cvt_pkrtz(a, b);
    return __builtin_bit_cast(u32, c);
}
// raw v_exp_f32 (single instruction, no OCML edge handling)
DEV float fexp2(float x) { return __builtin_amdgcn_exp2f(x); }

// ---------------- fused prep: gn_stats | weight convert | embedding GEMM ----------------
__global__ void prep_k(const float* __restrict__ x, float* __restrict__ stats,
                       const float* __restrict__ in_w, const float* __restrict__ out_w,
                       f16* __restrict__ w_in, f16* __restrict__ w_out,
                       const float* __restrict__ e, const float* __restrict__ ew,
                       const float* __restrict__ eb, float* __restrict__ embS) {
    int bid = blockIdx.x;
    if (bid < NB * NG) {
        // ---- GroupNorm stats: per-(b,g) mean/rstd ----
        int bg = bid;
        const float4* p = reinterpret_cast<const float4*>(x) + (size_t)bg * (CPG * HW / 4);
        float s = 0.f, ss = 0.f;
        for (int i = threadIdx.x; i < CPG * HW / 4; i += 256) {
            float4 v = p[i];
            s  += v.x + v.y + v.z + v.w;
            ss += v.x * v.x + v.y * v.y + v.z * v.z + v.w * v.w;
        }
        #pragma unroll
        for (int o = 32; o > 0; o >>= 1) {
            s  += __shfl_xor(s, o);
            ss += __shfl_xor(ss, o);
        }
        __shared__ float rs[4], rss[4];
        int wid = threadIdx.x >> 6;
        if ((threadIdx.x & 63) == 0) { rs[wid] = s; rss[wid] = ss; }
        __syncthreads();
        if (threadIdx.x == 0) {
            s  = rs[0] + rs[1] + rs[2] + rs[3];
            ss = rss[0] + rss[1] + rss[2] + rss[3];
            const float inv_n = 1.f / (float)(CPG * HW);
            float mean = s * inv_n;
            float var  = ss * inv_n - mean * mean;
            stats[bg * 2]     = mean;
            stats[bg * 2 + 1] = rsqrtf(var + 1e-5f);
        }
    } else if (bid < NB * NG + 512) {
        // ---- fp32 -> f16 weight conversion ----
        int i = (bid - NB * NG) * 256 + threadIdx.x;   // float4 index
        const int N1 = 3 * INNER * NC / 4;             // 98304
        float4 v;
        f16* dst;
        if (i < N1) { v = reinterpret_cast<const float4*>(in_w)[i];       dst = w_in + (size_t)i * 4; }
        else        { v = reinterpret_cast<const float4*>(out_w)[i - N1]; dst = w_out + (size_t)(i - N1) * 4; }
        f16x4 h4 = {(f16)v.x, (f16)v.y, (f16)v.z, (f16)v.w};
        *reinterpret_cast<f16x4*>(dst) = h4;
    } else {
        // ---- embedding scale: embS[b][co] = embedding[b,:] . emb_w[co,:] + emb_b ----
        int u = bid - (NB * NG + 512);   // 0..1023
        int b = u >> 6;
        int co = ((u & 63) << 2) + (threadIdx.x >> 6);
        int lane = threadIdx.x & 63;
        const float4* ep = reinterpret_cast<const float4*>(e + (size_t)b * TD);
        const float4* wp = reinterpret_cast<const float4*>(ew + (size_t)co * TD);
        float s = 0.f;
        for (int t = lane; t < TD / 4; t += 64) {
            float4 a = ep[t], w = wp[t];
            s += a.x * w.x + a.y * w.y + a.z * w.z + a.w * w.w;
        }
        #pragma unroll
        for (int o = 32; o > 0; o >>= 1) s += __shfl_xor(s, o);
        if (lane == 0) embS[b * NC + co] = s + eb[co];
    }
}

// ---------------- GroupNorm apply + transpose -> xnT[b][m][c] (f16) ----------------
// 512 blocks (2/CU): block = 32 m-rows; 8 threads per m-row, 32 channels each.
__global__ void gn_apply_k(const float* __restrict__ x, const float* __restrict__ stats,
                           const float* __restrict__ nw, const float* __restrict__ nb,
                           f16* __restrict__ xnT) {
    int b = blockIdx.y;
    int m = blockIdx.x * 32 + (threadIdx.x & 31);
    int c0 = (threadIdx.x >> 5) * 32;
    const float* xb = x + (size_t)b * NC * HW + m;
    f16* op = xnT + ((size_t)b * HW + m) * NC + c0;
    #pragma unroll
    for (int cc = 0; cc < 32; cc += 8) {
        int cg = c0 + cc;
        float mean = stats[(b * NG + (cg >> 3)) * 2];
        float rstd = stats[(b * NG + (cg >> 3)) * 2 + 1];
        f16x8 h;
        #pragma unroll
        for (int j = 0; j < 8; ++j) {
            int c = cg + j;
            float v = xb[(size_t)c * HW];
            h[j] = (f16)(((v - mean) * rstd) * nw[c] + nb[c]);
        }
        *reinterpret_cast<f16x8*>(op + cc) = h;
    }
}

// ---------------- GEMM fragment loader (A/B panels, stride = K dim) ----------------
DEV void ld_ab4(const f16* __restrict__ A, const f16* __restrict__ Bp, int k0, int stride,
                f16x8 (&af)[4], f16x8 (&bf)[4]) {
    #pragma unroll
    for (int i = 0; i < 4; ++i)
        af[i] = *reinterpret_cast<const f16x8*>(A + (size_t)i * 16 * stride + k0);
    #pragma unroll
    for (int j = 0; j < 4; ++j)
        bf[j] = *reinterpret_cast<const f16x8*>(Bp + (size_t)j * 16 * stride + k0);
}
DEV void mm44(const f16x8 (&af)[4], const f16x8 (&bf)[4], f32x4 (&acc)[4][4]) {
    #pragma unroll
    for (int i = 0; i < 4; ++i)
        #pragma unroll
        for (int j = 0; j < 4; ++j)
            acc[i][j] = mfma16(af[i], bf[j], acc[i][j]);
}

// ---------------- QKV GEMM: qkv[o,m] = in_w[o,:] . xn[b,:,m], scatter to q/k/v ----------------
// K pre-scaled by 0.125*log2(e). Pinned double-buffered K-loop (r13 technique).
__global__ __launch_bounds__(256, 2) void gemm_qkv_k(
        const f16* __restrict__ wA, const f16* __restrict__ xnT,
        const float* __restrict__ bias,
        f16* __restrict__ qT, f16* __restrict__ kT, f16* __restrict__ vv) {
    int bid = blockIdx.x;                       // 1536 = 8 * 192
    int u = (bid & 7) * 192 + (bid >> 3);
    int o0 = (u % 12) * 128;
    int rr = u / 12;                            // 0..127
    int m0 = (rr & 7) * 128;
    int b  = rr >> 3;
    int wid  = threadIdx.x >> 6;
    int lane = threadIdx.x & 63;
    int wr = (wid >> 1) * 64, wc = (wid & 1) * 64;
    int lr = lane & 15, lg = lane >> 4;

    const f16* A  = wA  + (size_t)(o0 + wr + lr) * NC + lg * 8;
    const f16* Bp = xnT + ((size_t)b * HW + m0 + wc + lr) * NC + lg * 8;

    const f32x4 fzero = {0.f, 0.f, 0.f, 0.f};
    f32x4 acc[4][4];
    #pragma unroll
    for (int i = 0; i < 4; ++i)
        #pragma unroll
        for (int j = 0; j < 4; ++j) acc[i][j] = fzero;

    // K=256 in 8 steps of 32: 4 groups of 2, pinned 1-deep prefetch
    f16x8 afA[4], bfA[4], afB[4], bfB[4];
    ld_ab4(A, Bp, 0, NC, afA, bfA); SB;
    #pragma unroll 1
    for (int g = 0; g < 4; ++g) {
        int k0 = g * 64;
        ld_ab4(A, Bp, k0 + 32, NC, afB, bfB); SB;       // <= 224, always valid
        mm44(afA, bfA, acc); SB;
        if (g < 3) { ld_ab4(A, Bp, k0 + 64, NC, afA, bfA); } SB;
        mm44(afB, bfB, acc); SB;
    }

    const float SL = 0.18033688011112042f;  // 0.125 * log2(e)
    #pragma unroll
    for (int i = 0; i < 4; ++i) {
        int ob = o0 + wr + i * 16 + lg * 4;  // first of 4 consecutive output rows
        #pragma unroll
        for (int j = 0; j < 4; ++j) {
            int m = m0 + wc + j * 16 + lr;
            float v0 = acc[i][j][0] + bias[ob];
            float v1 = acc[i][j][1] + bias[ob + 1];
            float v2 = acc[i][j][2] + bias[ob + 2];
            float v3 = acc[i][j][3] + bias[ob + 3];
            if (ob < INNER) {                      // Q -> qT[bh][m][c]
                int h = ob >> 6, c = ob & 63;
                f16x4 pk = {(f16)v0, (f16)v1, (f16)v2, (f16)v3};
                *reinterpret_cast<f16x4*>(qT + (((size_t)(b * NH + h) * HW + m) * HD + c)) = pk;
            } else if (ob < 2 * INNER) {           // K -> kT[bh][n][c], pre-scaled
                int oo = ob - INNER;
                int h = oo >> 6, c = oo & 63;
                f16x4 pk = {(f16)(v0 * SL), (f16)(v1 * SL), (f16)(v2 * SL), (f16)(v3 * SL)};
                *reinterpret_cast<f16x4*>(kT + (((size_t)(b * NH + h) * HW + m) * HD + c)) = pk;
            } else {                               // V -> v[bh][c][n]
                int oo = ob - 2 * INNER;
                int h = oo >> 6, c = oo & 63;
                f16* vp = vv + ((size_t)(b * NH + h) * HD + c) * HW + m;
                vp[0]      = (f16)v0;
                vp[HW]     = (f16)v1;
                vp[2 * HW] = (f16)v2;
                vp[3 * HW] = (f16)v3;
            }
        }
    }
}

// ---------------- flash attention helpers ----------------
// Key-permuted K load: A(sc0) row i holds physical key 8*(i>>2)+(i&3),
// A(sc1) row i holds key 8*(i>>2)+4+(i&3). Softmax is key-permutation
// invariant; V is consumed in physical-key order, and with this permutation
// lane (lr,lg)'s S^T outputs are exactly keys 8*lg+{0..7} -- the PV B-fragment
// layout. P never leaves registers (no LDS).
DEV void load_kv(const f16* __restrict__ kp0, const f16* __restrict__ vp,
                 int n0, int lr, int lg, f16x8 (&kf)[2][2], f16x8 (&vf)[4]) {
    const f16* p0 = kp0 + (size_t)n0 * HD;
    kf[0][0] = *reinterpret_cast<const f16x8*>(p0);
    kf[0][1] = *reinterpret_cast<const f16x8*>(p0 + 32);
    kf[1][0] = *reinterpret_cast<const f16x8*>(p0 + 4 * HD);
    kf[1][1] = *reinterpret_cast<const f16x8*>(p0 + 4 * HD + 32);
    #pragma unroll
    for (int dt = 0; dt < 4; ++dt)
        vf[dt] = *reinterpret_cast<const f16x8*>(
            vp + (size_t)(dt * 16 + lr) * HW + n0 + lg * 8);
}

// One 32-key tile, chained per qt, all-register P (no LDS). Scores arrive in
// log2 units (K pre-scaled). Maps: round-1-verified 16x16x32 only.
DEV void attn_tile(const f16x8 (&kf)[2][2], const f16x8 (&vf)[4],
                   const f16x8 (&qf)[4][2],
                   f32x4 (&oa)[4][4], float (&mr)[4], float (&lsl)[4]) {
    const float THR = 11.0f;   // p <= 2^11, f16-safe
    const f32x4 fzero = {0.f, 0.f, 0.f, 0.f};
    #pragma unroll
    for (int qt = 0; qt < 4; ++qt) {
        f32x4 sc0 = fzero, sc1 = fzero;
        __builtin_amdgcn_s_setprio(1);
        sc0 = mfma16(kf[0][0], qf[qt][0], sc0);
        sc0 = mfma16(kf[0][1], qf[qt][1], sc0);
        sc1 = mfma16(kf[1][0], qf[qt][0], sc1);
        sc1 = mfma16(kf[1][1], qf[qt][1], sc1);
        __builtin_amdgcn_s_setprio(0);

        // lane (lr,lg): sc0[r] = key 8lg+r, sc1[r] = key 8lg+4+r (log2 units)
        float m0 = fmaxf(fmaxf(sc0[0], sc0[1]), fmaxf(sc0[2], sc0[3]));
        float m1 = fmaxf(fmaxf(sc1[0], sc1[1]), fmaxf(sc1[2], sc1[3]));
        float pmax = fmaxf(m0, m1);
        if (__any(pmax - mr[qt] > THR)) {   // rare: first tile + big max jumps
            float pm = pmax;
            pm = fmaxf(pm, __shfl_xor(pm, 16));
            pm = fmaxf(pm, __shfl_xor(pm, 32));
            float mn = fmaxf(mr[qt], pm);
            float f = fexp2(mr[qt] - mn);   // first tile: exp2(-huge) = 0
            mr[qt] = mn;
            lsl[qt] *= f;
            #pragma unroll
            for (int dt = 0; dt < 4; ++dt)
                #pragma unroll
                for (int r = 0; r < 4; ++r) oa[qt][dt][r] *= f;
        }
        float p[8];
        #pragma unroll
        for (int r = 0; r < 4; ++r) p[r]     = fexp2(sc0[r] - mr[qt]);
        #pragma unroll
        for (int r = 0; r < 4; ++r) p[4 + r] = fexp2(sc1[r] - mr[qt]);
        lsl[qt] += ((p[0] + p[1]) + (p[2] + p[3])) + ((p[4] + p[5]) + (p[6] + p[7]));

        // PV B-fragment built fully in-register: element j = key 8lg+j
        union { u32 u[4]; f16x8 v; } pfu;
        pfu.u[0] = pk2(p[0], p[1]);
        pfu.u[1] = pk2(p[2], p[3]);
        pfu.u[2] = pk2(p[4], p[5]);
        pfu.u[3] = pk2(p[6], p[7]);

        __builtin_amdgcn_s_setprio(1);
        #pragma unroll
        for (int dt = 0; dt < 4; ++dt)
            oa[qt][dt] = mfma16(vf[dt], pfu.v, oa[qt][dt]);
        __builtin_amdgcn_s_setprio(0);
    }
}

// ---------------- flash attention: 64 q/wave, pinned 2-deep prefetch, no LDS ----------------
// r13/r15 configuration (measured 77.6 us twice): 3 buffers / 2 tiles in
// flight, launch_bounds(256,2), VGPR=120, no scratch. r14 (depth 3) spilled;
// r16 (512-thread TLP) spilled catastrophically (VGPR=64, 250 MB scratch).
// This structure needs >=120 VGPR -> 2 waves/SIMD is its residency optimum.
__global__ __launch_bounds__(256, 2) void attn_k(
        const f16* __restrict__ qT, const f16* __restrict__ kT, const f16* __restrict__ vv,
        f16* __restrict__ oT) {
    // XCD swizzle: 512 blocks, bid%8 -> XCD; give each XCD 16 whole bh's
    int u = ((blockIdx.x & 7) << 6) | (blockIdx.x >> 3);
    int bh = u >> 2;               // b*NH + h
    int mt = u & 3;
    int b = bh >> 3, h = bh & 7;
    int wid = threadIdx.x >> 6;
    int lane = threadIdx.x & 63;
    int lr = lane & 15, lg = lane >> 4;
    int mw = mt * 256 + wid * 64;

    const f16* qp = qT + (size_t)bh * HW * HD;
    // permuted K base: lane reads physical key row 8*(lr>>2)+(lr&3) (+4 for sc1)
    const f16* kp0 = kT + (size_t)bh * HW * HD
                   + (size_t)(8 * (lr >> 2) + (lr & 3)) * HD + lg * 8;
    const f16* vp = vv + (size_t)bh * HD * HW;

    // Q fragments (B-operand): col=q=lr, k = d = ks2*32 + lg*8 + j
    f16x8 qf[4][2];
    #pragma unroll
    for (int qt = 0; qt < 4; ++qt)
        #pragma unroll
        for (int ks2 = 0; ks2 < 2; ++ks2)
            qf[qt][ks2] = *reinterpret_cast<const f16x8*>(
                qp + (size_t)(mw + qt * 16 + lr) * HD + ks2 * 32 + lg * 8);

    const f32x4 fzero = {0.f, 0.f, 0.f, 0.f};
    f32x4 oa[4][4];                // [qt][dt] : O^T[d=dt*16+lg*4+r][q=qt*16+lr]
    #pragma unroll
    for (int qt = 0; qt < 4; ++qt)
        #pragma unroll
        for (int dt = 0; dt < 4; ++dt) oa[qt][dt] = fzero;
    float mr[4]  = {-1e30f, -1e30f, -1e30f, -1e30f};
    float lsl[4] = {0.f, 0.f, 0.f, 0.f};   // per-lane partial denominators

    // 3-buffer rotation, 2 tiles in flight, issue order PINNED.
    // 32 tiles = 10 groups of 3 + 2 epilogue. Max load index = t31. No OOB.
    f16x8 kfA[2][2], vfA[4], kfB[2][2], vfB[4], kfC[2][2], vfC[4];
    load_kv(kp0, vp, 0,  lr, lg, kfA, vfA); SB;
    load_kv(kp0, vp, 32, lr, lg, kfB, vfB); SB;
    #pragma unroll 1
    for (int g = 0; g < 10; ++g) {
        int n0 = g * 96;
        load_kv(kp0, vp, n0 + 64, lr, lg, kfC, vfC); SB;
        attn_tile(kfA, vfA, qf, oa, mr, lsl); SB;
        load_kv(kp0, vp, n0 + 96, lr, lg, kfA, vfA); SB;
        attn_tile(kfB, vfB, qf, oa, mr, lsl); SB;
        load_kv(kp0, vp, n0 + 128, lr, lg, kfB, vfB); SB;
        attn_tile(kfC, vfC, qf, oa, mr, lsl); SB;
    }
    attn_tile(kfA, vfA, qf, oa, mr, lsl);   // t30
    attn_tile(kfB, vfB, qf, oa, mr, lsl);   // t31

    // finalize: reduce per-lane partials across the 4 lg lanes per query
    #pragma unroll
    for (int qt = 0; qt < 4; ++qt) {
        float t = lsl[qt];
        t += __shfl_xor(t, 16);
        t += __shfl_xor(t, 32);
        float inv = 1.f / t;
        int m = mw + qt * 16 + lr;
        f16* op = oT + ((size_t)b * HW + m) * INNER + h * HD;
        #pragma unroll
        for (int dt = 0; dt < 4; ++dt) {
            f16x4 o4;
            #pragma unroll
            for (int r = 0; r < 4; ++r) o4[r] = (f16)(oa[qt][dt][r] * inv);
            *reinterpret_cast<f16x4*>(op + dt * 16 + lg * 4) = o4;
        }
    }
}

// ---------------- out projection + bias + emb-scale + residual ----------------
// 64x128 tiles -> 512 blocks (2/CU), XCD-chunk swizzle, pinned dbuf K-loop.
__global__ __launch_bounds__(256) void gemm_out_k(
        const f16* __restrict__ wA, const f16* __restrict__ oT,
        const float* __restrict__ bias, const float* __restrict__ embS,
        const float* __restrict__ x, float* __restrict__ out) {
    int bid = blockIdx.x;                       // 512 = 8 * 64
    int u = (bid & 7) * 64 + (bid >> 3);
    int o0 = (u & 3) * 64;
    int rr = u >> 2;                            // 0..127
    int m0 = (rr & 7) * 128;
    int b  = rr >> 3;
    int wid  = threadIdx.x >> 6;
    int lane = threadIdx.x & 63;
    int wr = (wid >> 1) * 32, wc = (wid & 1) * 64;
    int lr = lane & 15, lg = lane >> 4;

    const f16* A  = wA + (size_t)(o0 + wr + lr) * INNER + lg * 8;
    const f16* Bp = oT + ((size_t)b * HW + m0 + wc + lr) * INNER + lg * 8;

    const f32x4 fzero = {0.f, 0.f, 0.f, 0.f};
    f32x4 acc[2][4];
    #pragma unroll
    for (int i = 0; i < 2; ++i)
        #pragma unroll
        for (int j = 0; j < 4; ++j) acc[i][j] = fzero;

    // K=512 in 16 steps of 32: 8 groups of 2, pinned 1-deep prefetch
    f16x8 afA[2], bfA[4], afB[2], bfB[4];
    auto ld = [&](int k0, f16x8 (&af)[2], f16x8 (&bf)[4]) {
        #pragma unroll
        for (int i = 0; i < 2; ++i)
            af[i] = *reinterpret_cast<const f16x8*>(A + (size_t)i * 16 * INNER + k0);
        #pragma unroll
        for (int j = 0; j < 4; ++j)
            bf[j] = *reinterpret_cast<const f16x8*>(Bp + (size_t)j * 16 * INNER + k0);
    };
    auto mm = [&](const f16x8 (&af)[2], const f16x8 (&bf)[4]) {
        #pragma unroll
        for (int i = 0; i < 2; ++i)
            #pragma unroll
            for (int j = 0; j < 4; ++j)
                acc[i][j] = mfma16(af[i], bf[j], acc[i][j]);
    };
    ld(0, afA, bfA); SB;
    #pragma unroll 1
    for (int g = 0; g < 8; ++g) {
        int k0 = g * 64;
        ld(k0 + 32, afB, bfB); SB;                    // <= 480, always valid
        mm(afA, bfA); SB;
        if (g < 7) { ld(k0 + 64, afA, bfA); } SB;
        mm(afB, bfB); SB;
    }

    #pragma unroll
    for (int i = 0; i < 2; ++i) {
        int ob = o0 + wr + i * 16 + lg * 4;
        #pragma unroll
        for (int j = 0; j < 4; ++j) {
            int m = m0 + wc + j * 16 + lr;
            #pragma unroll
            for (int r = 0; r < 4; ++r) {
                int o = ob + r;
                size_t idx = ((size_t)b * NC + o) * HW + m;
                out[idx] = (acc[i][j][r] + bias[o]) * embS[b * NC + o] + x[idx];
            }
        }
    }
}

extern "C" void kernel_launch(void* const* d_in, const int* in_sizes, int n_in,
                              void* d_out, int out_size, void* d_ws, size_t ws_size,
                              hipStream_t stream) {
    const float* x     = (const float*)d_in[0];
    const float* emb   = (const float*)d_in[1];
    const float* nw    = (const float*)d_in[2];
    const float* nbi   = (const float*)d_in[3];
    const float* in_w  = (const float*)d_in[4];
    const float* in_b  = (const float*)d_in[5];
    const float* out_w = (const float*)d_in[6];
    const float* out_b = (const float*)d_in[7];
    const float* emb_w = (const float*)d_in[8];
    const float* emb_b = (const float*)d_in[9];

    char* p = (char*)d_ws;
    f16* xnT   = (f16*)p;   p += (size_t)NB * HW * NC * 2;        // 8 MB
    f16* w_in  = (f16*)p;   p += (size_t)3 * INNER * NC * 2;      // 768 KB
    f16* w_out = (f16*)p;   p += (size_t)NC * INNER * 2;          // 256 KB
    float* stats = (float*)p; p += (size_t)NB * NG * 2 * 4;       // 4 KB
    float* embS  = (float*)p; p += (size_t)NB * NC * 4;           // 16 KB
    f16* qT = (f16*)p;      p += (size_t)NB * NH * HW * HD * 2;   // 16 MB
    f16* kT = (f16*)p;      p += (size_t)NB * NH * HW * HD * 2;   // 16 MB
    f16* vv = (f16*)p;      p += (size_t)NB * NH * HW * HD * 2;   // 16 MB
    f16* oT = (f16*)p;                                            // 16 MB

    prep_k<<<NB * NG + 512 + 1024, 256, 0, stream>>>(x, stats, in_w, out_w, w_in, w_out,
                                                     emb, emb_w, emb_b, embS);
    gn_apply_k<<<dim3(HW / 32, NB), 256, 0, stream>>>(x, stats, nw, nbi, xnT);
    gemm_qkv_k<<<1536, 256, 0, stream>>>(w_in, xnT, in_b, qT, kT, vv);
    attn_k<<<512, 256, 0, stream>>>(qT, kT, vv, oT);
    gemm_out_k<<<512, 256, 0, stream>>>(w_out, oT, out_b, embS, x, (float*)d_out);
}

// Round 18
// 158.057 us; speedup vs baseline: 1.7756x; 1.0028x over previous
//
#include <hip/hip_runtime.h>

#define DEV __device__ __forceinline__
#define SB __builtin_amdgcn_sched_barrier(0)

typedef _Float16 f16;
typedef _Float16 f16x8 __attribute__((ext_vector_type(8)));
typedef _Float16 f16x4 __attribute__((ext_vector_type(4)));
typedef float f32x4 __attribute__((ext_vector_type(4)));
typedef unsigned int u32;

static constexpr int NB = 16;       // batch
static constexpr int NC = 256;      // channels
static constexpr int HW = 1024;     // h*w
static constexpr int NG = 32;       // groups
static constexpr int CPG = 8;       // channels per group
static constexpr int NH = 8;        // heads
static constexpr int HD = 64;       // head dim
static constexpr int INNER = 512;   // heads*head_dim
static constexpr int TD = 1024;     // time-embedding dim

DEV f32x4 mfma16(f16x8 a, f16x8 b, f32x4 c) {
    return __builtin_amdgcn_mfma_f32_16x16x32_f16(a, b, c, 0, 0, 0);
}

// pack two f32 -> one dword of two f16 (RTZ)
DEV u32 pk2(float a, float b) {
    auto c = __builtin_amdgcn_cvt_pkrtz(a, b);
    return __builtin_bit_cast(u32, c);
}
// raw v_exp_f32 (single instruction, no OCML edge handling)
DEV float fexp2(float x) { return __builtin_amdgcn_exp2f(x); }

// ---------------- fused prep: gn_stats | weight convert | embedding GEMM ----------------
__global__ void prep_k(const float* __restrict__ x, float* __restrict__ stats,
                       const float* __restrict__ in_w, const float* __restrict__ out_w,
                       f16* __restrict__ w_in, f16* __restrict__ w_out,
                       const float* __restrict__ e, const float* __restrict__ ew,
                       const float* __restrict__ eb, float* __restrict__ embS) {
    int bid = blockIdx.x;
    if (bid < NB * NG) {
        // ---- GroupNorm stats: per-(b,g) mean/rstd ----
        int bg = bid;
        const float4* p = reinterpret_cast<const float4*>(x) + (size_t)bg * (CPG * HW / 4);
        float s = 0.f, ss = 0.f;
        for (int i = threadIdx.x; i < CPG * HW / 4; i += 256) {
            float4 v = p[i];
            s  += v.x + v.y + v.z + v.w;
            ss += v.x * v.x + v.y * v.y + v.z * v.z + v.w * v.w;
        }
        #pragma unroll
        for (int o = 32; o > 0; o >>= 1) {
            s  += __shfl_xor(s, o);
            ss += __shfl_xor(ss, o);
        }
        __shared__ float rs[4], rss[4];
        int wid = threadIdx.x >> 6;
        if ((threadIdx.x & 63) == 0) { rs[wid] = s; rss[wid] = ss; }
        __syncthreads();
        if (threadIdx.x == 0) {
            s  = rs[0] + rs[1] + rs[2] + rs[3];
            ss = rss[0] + rss[1] + rss[2] + rss[3];
            const float inv_n = 1.f / (float)(CPG * HW);
            float mean = s * inv_n;
            float var  = ss * inv_n - mean * mean;
            stats[bg * 2]     = mean;
            stats[bg * 2 + 1] = rsqrtf(var + 1e-5f);
        }
    } else if (bid < NB * NG + 512) {
        // ---- fp32 -> f16 weight conversion ----
        int i = (bid - NB * NG) * 256 + threadIdx.x;   // float4 index
        const int N1 = 3 * INNER * NC / 4;             // 98304
        float4 v;
        f16* dst;
        if (i < N1) { v = reinterpret_cast<const float4*>(in_w)[i];       dst = w_in + (size_t)i * 4; }
        else        { v = reinterpret_cast<const float4*>(out_w)[i - N1]; dst = w_out + (size_t)(i - N1) * 4; }
        f16x4 h4 = {(f16)v.x, (f16)v.y, (f16)v.z, (f16)v.w};
        *reinterpret_cast<f16x4*>(dst) = h4;
    } else {
        // ---- embedding scale: embS[b][co] = embedding[b,:] . emb_w[co,:] + emb_b ----
        int u = bid - (NB * NG + 512);   // 0..1023
        int b = u >> 6;
        int co = ((u & 63) << 2) + (threadIdx.x >> 6);
        int lane = threadIdx.x & 63;
        const float4* ep = reinterpret_cast<const float4*>(e + (size_t)b * TD);
        const float4* wp = reinterpret_cast<const float4*>(ew + (size_t)co * TD);
        float s = 0.f;
        for (int t = lane; t < TD / 4; t += 64) {
            float4 a = ep[t], w = wp[t];
            s += a.x * w.x + a.y * w.y + a.z * w.z + a.w * w.w;
        }
        #pragma unroll
        for (int o = 32; o > 0; o >>= 1) s += __shfl_xor(s, o);
        if (lane == 0) embS[b * NC + co] = s + eb[co];
    }
}

// ---------------- GroupNorm apply + transpose -> xnT[b][m][c] (f16) ----------------
// 512 blocks (2/CU): block = 32 m-rows; 8 threads per m-row, 32 channels each.
__global__ void gn_apply_k(const float* __restrict__ x, const float* __restrict__ stats,
                           const float* __restrict__ nw, const float* __restrict__ nb,
                           f16* __restrict__ xnT) {
    int b = blockIdx.y;
    int m = blockIdx.x * 32 + (threadIdx.x & 31);
    int c0 = (threadIdx.x >> 5) * 32;
    const float* xb = x + (size_t)b * NC * HW + m;
    f16* op = xnT + ((size_t)b * HW + m) * NC + c0;
    #pragma unroll
    for (int cc = 0; cc < 32; cc += 8) {
        int cg = c0 + cc;
        float mean = stats[(b * NG + (cg >> 3)) * 2];
        float rstd = stats[(b * NG + (cg >> 3)) * 2 + 1];
        f16x8 h;
        #pragma unroll
        for (int j = 0; j < 8; ++j) {
            int c = cg + j;
            float v = xb[(size_t)c * HW];
            h[j] = (f16)(((v - mean) * rstd) * nw[c] + nb[c]);
        }
        *reinterpret_cast<f16x8*>(op + cc) = h;
    }
}

// ---------------- GEMM fragment loader (A/B panels, stride = K dim) ----------------
DEV void ld_ab4(const f16* __restrict__ A, const f16* __restrict__ Bp, int k0, int stride,
                f16x8 (&af)[4], f16x8 (&bf)[4]) {
    #pragma unroll
    for (int i = 0; i < 4; ++i)
        af[i] = *reinterpret_cast<const f16x8*>(A + (size_t)i * 16 * stride + k0);
    #pragma unroll
    for (int j = 0; j < 4; ++j)
        bf[j] = *reinterpret_cast<const f16x8*>(Bp + (size_t)j * 16 * stride + k0);
}
DEV void mm44(const f16x8 (&af)[4], const f16x8 (&bf)[4], f32x4 (&acc)[4][4]) {
    #pragma unroll
    for (int i = 0; i < 4; ++i)
        #pragma unroll
        for (int j = 0; j < 4; ++j)
            acc[i][j] = mfma16(af[i], bf[j], acc[i][j]);
}

// ---------------- QKV GEMM: qkv[o,m] = in_w[o,:] . xn[b,:,m], scatter to q/k/v ----------------
// K pre-scaled by 0.125*log2(e). Pinned double-buffered K-loop (r13 technique).
__global__ __launch_bounds__(256, 2) void gemm_qkv_k(
        const f16* __restrict__ wA, const f16* __restrict__ xnT,
        const float* __restrict__ bias,
        f16* __restrict__ qT, f16* __restrict__ kT, f16* __restrict__ vv) {
    int bid = blockIdx.x;                       // 1536 = 8 * 192
    int u = (bid & 7) * 192 + (bid >> 3);
    int o0 = (u % 12) * 128;
    int rr = u / 12;                            // 0..127
    int m0 = (rr & 7) * 128;
    int b  = rr >> 3;
    int wid  = threadIdx.x >> 6;
    int lane = threadIdx.x & 63;
    int wr = (wid >> 1) * 64, wc = (wid & 1) * 64;
    int lr = lane & 15, lg = lane >> 4;

    const f16* A  = wA  + (size_t)(o0 + wr + lr) * NC + lg * 8;
    const f16* Bp = xnT + ((size_t)b * HW + m0 + wc + lr) * NC + lg * 8;

    const f32x4 fzero = {0.f, 0.f, 0.f, 0.f};
    f32x4 acc[4][4];
    #pragma unroll
    for (int i = 0; i < 4; ++i)
        #pragma unroll
        for (int j = 0; j < 4; ++j) acc[i][j] = fzero;

    // K=256 in 8 steps of 32: 4 groups of 2, pinned 1-deep prefetch
    f16x8 afA[4], bfA[4], afB[4], bfB[4];
    ld_ab4(A, Bp, 0, NC, afA, bfA); SB;
    #pragma unroll 1
    for (int g = 0; g < 4; ++g) {
        int k0 = g * 64;
        ld_ab4(A, Bp, k0 + 32, NC, afB, bfB); SB;       // <= 224, always valid
        mm44(afA, bfA, acc); SB;
        if (g < 3) { ld_ab4(A, Bp, k0 + 64, NC, afA, bfA); } SB;
        mm44(afB, bfB, acc); SB;
    }

    const float SL = 0.18033688011112042f;  // 0.125 * log2(e)
    #pragma unroll
    for (int i = 0; i < 4; ++i) {
        int ob = o0 + wr + i * 16 + lg * 4;  // first of 4 consecutive output rows
        #pragma unroll
        for (int j = 0; j < 4; ++j) {
            int m = m0 + wc + j * 16 + lr;
            float v0 = acc[i][j][0] + bias[ob];
            float v1 = acc[i][j][1] + bias[ob + 1];
            float v2 = acc[i][j][2] + bias[ob + 2];
            float v3 = acc[i][j][3] + bias[ob + 3];
            if (ob < INNER) {                      // Q -> qT[bh][m][c]
                int h = ob >> 6, c = ob & 63;
                f16x4 pk = {(f16)v0, (f16)v1, (f16)v2, (f16)v3};
                *reinterpret_cast<f16x4*>(qT + (((size_t)(b * NH + h) * HW + m) * HD + c)) = pk;
            } else if (ob < 2 * INNER) {           // K -> kT[bh][n][c], pre-scaled
                int oo = ob - INNER;
                int h = oo >> 6, c = oo & 63;
                f16x4 pk = {(f16)(v0 * SL), (f16)(v1 * SL), (f16)(v2 * SL), (f16)(v3 * SL)};
                *reinterpret_cast<f16x4*>(kT + (((size_t)(b * NH + h) * HW + m) * HD + c)) = pk;
            } else {                               // V -> v[bh][c][n]
                int oo = ob - 2 * INNER;
                int h = oo >> 6, c = oo & 63;
                f16* vp = vv + ((size_t)(b * NH + h) * HD + c) * HW + m;
                vp[0]      = (f16)v0;
                vp[HW]     = (f16)v1;
                vp[2 * HW] = (f16)v2;
                vp[3 * HW] = (f16)v3;
            }
        }
    }
}

// ---------------- flash attention helpers ----------------
// Key-permuted K load: A(sc0) row i holds physical key 8*(i>>2)+(i&3),
// A(sc1) row i holds key 8*(i>>2)+4+(i&3). Softmax is key-permutation
// invariant; V is consumed in physical-key order, and with this permutation
// lane (lr,lg)'s S^T outputs are exactly keys 8*lg+{0..7} -- the PV B-fragment
// layout. P never leaves registers (no LDS).
DEV void load_kv(const f16* __restrict__ kp0, const f16* __restrict__ vp,
                 int n0, int lr, int lg, f16x8 (&kf)[2][2], f16x8 (&vf)[4]) {
    const f16* p0 = kp0 + (size_t)n0 * HD;
    kf[0][0] = *reinterpret_cast<const f16x8*>(p0);
    kf[0][1] = *reinterpret_cast<const f16x8*>(p0 + 32);
    kf[1][0] = *reinterpret_cast<const f16x8*>(p0 + 4 * HD);
    kf[1][1] = *reinterpret_cast<const f16x8*>(p0 + 4 * HD + 32);
    #pragma unroll
    for (int dt = 0; dt < 4; ++dt)
        vf[dt] = *reinterpret_cast<const f16x8*>(
            vp + (size_t)(dt * 16 + lr) * HW + n0 + lg * 8);
}

// One 32-key tile, chained per qt, all-register P (no LDS). Scores arrive in
// log2 units (K pre-scaled). Maps: round-1-verified 16x16x32 only.
DEV void attn_tile(const f16x8 (&kf)[2][2], const f16x8 (&vf)[4],
                   const f16x8 (&qf)[4][2],
                   f32x4 (&oa)[4][4], float (&mr)[4], float (&lsl)[4]) {
    const float THR = 11.0f;   // p <= 2^11, f16-safe
    const f32x4 fzero = {0.f, 0.f, 0.f, 0.f};
    #pragma unroll
    for (int qt = 0; qt < 4; ++qt) {
        f32x4 sc0 = fzero, sc1 = fzero;
        __builtin_amdgcn_s_setprio(1);
        sc0 = mfma16(kf[0][0], qf[qt][0], sc0);
        sc0 = mfma16(kf[0][1], qf[qt][1], sc0);
        sc1 = mfma16(kf[1][0], qf[qt][0], sc1);
        sc1 = mfma16(kf[1][1], qf[qt][1], sc1);
        __builtin_amdgcn_s_setprio(0);

        // lane (lr,lg): sc0[r] = key 8lg+r, sc1[r] = key 8lg+4+r (log2 units)
        float m0 = fmaxf(fmaxf(sc0[0], sc0[1]), fmaxf(sc0[2], sc0[3]));
        float m1 = fmaxf(fmaxf(sc1[0], sc1[1]), fmaxf(sc1[2], sc1[3]));
        float pmax = fmaxf(m0, m1);
        if (__any(pmax - mr[qt] > THR)) {   // rare: first tile + big max jumps
            float pm = pmax;
            pm = fmaxf(pm, __shfl_xor(pm, 16));
            pm = fmaxf(pm, __shfl_xor(pm, 32));
            float mn = fmaxf(mr[qt], pm);
            float f = fexp2(mr[qt] - mn);   // first tile: exp2(-huge) = 0
            mr[qt] = mn;
            lsl[qt] *= f;
            #pragma unroll
            for (int dt = 0; dt < 4; ++dt)
                #pragma unroll
                for (int r = 0; r < 4; ++r) oa[qt][dt][r] *= f;
        }
        float p[8];
        #pragma unroll
        for (int r = 0; r < 4; ++r) p[r]     = fexp2(sc0[r] - mr[qt]);
        #pragma unroll
        for (int r = 0; r < 4; ++r) p[4 + r] = fexp2(sc1[r] - mr[qt]);
        lsl[qt] += ((p[0] + p[1]) + (p[2] + p[3])) + ((p[4] + p[5]) + (p[6] + p[7]));

        // PV B-fragment built fully in-register: element j = key 8lg+j
        union { u32 u[4]; f16x8 v; } pfu;
        pfu.u[0] = pk2(p[0], p[1]);
        pfu.u[1] = pk2(p[2], p[3]);
        pfu.u[2] = pk2(p[4], p[5]);
        pfu.u[3] = pk2(p[6], p[7]);

        __builtin_amdgcn_s_setprio(1);
        #pragma unroll
        for (int dt = 0; dt < 4; ++dt)
            oa[qt][dt] = mfma16(vf[dt], pfu.v, oa[qt][dt]);
        __builtin_amdgcn_s_setprio(0);
    }
}

// ---------------- flash attention: 8-wave blocks, 64 q/wave, pinned 2-deep, no LDS ----------------
// Occupancy fix: r16 proved 512-thread blocks actually stack to >=4 waves/SIMD
// (43% occupancy) while 256-thread blocks never exceed ~2 (r8/r15: ~20%).
// r16 failed only because launch_bounds(512,4) forced a 64-VGPR allocation
// (250 MB scratch). Here: bound (512,2) caps at 256 VGPR (non-binding; the
// r15 per-wave code allocates ~120), so HW can opportunistically co-schedule
// 4 waves/SIMD (4 x 120 = 480 <= 512 VGPR pool, LDS = 0). Per-wave code is
// byte-identical to the twice-measured 77-us r15/r17 kernel.
__global__ __launch_bounds__(512, 2) void attn_k(
        const f16* __restrict__ qT, const f16* __restrict__ kT, const f16* __restrict__ vv,
        f16* __restrict__ oT) {
    // XCD swizzle: 256 blocks, bid%8 -> XCD; each XCD gets 16 whole bh's
    int u = ((blockIdx.x & 7) << 5) | (blockIdx.x >> 3);   // 0..255
    int bh = u >> 1;               // b*NH + h
    int half = u & 1;
    int b = bh >> 3, h = bh & 7;
    int wid = threadIdx.x >> 6;    // 0..7
    int lane = threadIdx.x & 63;
    int lr = lane & 15, lg = lane >> 4;
    int mw = half * 512 + wid * 64;   // 8 waves x 64 q = 512 q per block

    const f16* qp = qT + (size_t)bh * HW * HD;
    // permuted K base: lane reads physical key row 8*(lr>>2)+(lr&3) (+4 for sc1)
    const f16* kp0 = kT + (size_t)bh * HW * HD
                   + (size_t)(8 * (lr >> 2) + (lr & 3)) * HD + lg * 8;
    const f16* vp = vv + (size_t)bh * HD * HW;

    // Q fragments (B-operand): col=q=lr, k = d = ks2*32 + lg*8 + j
    f16x8 qf[4][2];
    #pragma unroll
    for (int qt = 0; qt < 4; ++qt)
        #pragma unroll
        for (int ks2 = 0; ks2 < 2; ++ks2)
            qf[qt][ks2] = *reinterpret_cast<const f16x8*>(
                qp + (size_t)(mw + qt * 16 + lr) * HD + ks2 * 32 + lg * 8);

    const f32x4 fzero = {0.f, 0.f, 0.f, 0.f};
    f32x4 oa[4][4];                // [qt][dt] : O^T[d=dt*16+lg*4+r][q=qt*16+lr]
    #pragma unroll
    for (int qt = 0; qt < 4; ++qt)
        #pragma unroll
        for (int dt = 0; dt < 4; ++dt) oa[qt][dt] = fzero;
    float mr[4]  = {-1e30f, -1e30f, -1e30f, -1e30f};
    float lsl[4] = {0.f, 0.f, 0.f, 0.f};   // per-lane partial denominators

    // 3-buffer rotation, 2 tiles in flight, issue order PINNED.
    // 32 tiles = 10 groups of 3 + 2 epilogue. Max load index = t31. No OOB.
    f16x8 kfA[2][2], vfA[4], kfB[2][2], vfB[4], kfC[2][2], vfC[4];
    load_kv(kp0, vp, 0,  lr, lg, kfA, vfA); SB;
    load_kv(kp0, vp, 32, lr, lg, kfB, vfB); SB;
    #pragma unroll 1
    for (int g = 0; g < 10; ++g) {
        int n0 = g * 96;
        load_kv(kp0, vp, n0 + 64, lr, lg, kfC, vfC); SB;
        attn_tile(kfA, vfA, qf, oa, mr, lsl); SB;
        load_kv(kp0, vp, n0 + 96, lr, lg, kfA, vfA); SB;
        attn_tile(kfB, vfB, qf, oa, mr, lsl); SB;
        load_kv(kp0, vp, n0 + 128, lr, lg, kfB, vfB); SB;
        attn_tile(kfC, vfC, qf, oa, mr, lsl); SB;
    }
    attn_tile(kfA, vfA, qf, oa, mr, lsl);   // t30
    attn_tile(kfB, vfB, qf, oa, mr, lsl);   // t31

    // finalize: reduce per-lane partials across the 4 lg lanes per query
    #pragma unroll
    for (int qt = 0; qt < 4; ++qt) {
        float t = lsl[qt];
        t += __shfl_xor(t, 16);
        t += __shfl_xor(t, 32);
        float inv = 1.f / t;
        int m = mw + qt * 16 + lr;
        f16* op = oT + ((size_t)b * HW + m) * INNER + h * HD;
        #pragma unroll
        for (int dt = 0; dt < 4; ++dt) {
            f16x4 o4;
            #pragma unroll
            for (int r = 0; r < 4; ++r) o4[r] = (f16)(oa[qt][dt][r] * inv);
            *reinterpret_cast<f16x4*>(op + dt * 16 + lg * 4) = o4;
        }
    }
}

// ---------------- out projection + bias + emb-scale + residual ----------------
// 64x128 tiles -> 512 blocks (2/CU), XCD-chunk swizzle, pinned dbuf K-loop.
__global__ __launch_bounds__(256) void gemm_out_k(
        const f16* __restrict__ wA, const f16* __restrict__ oT,
        const float* __restrict__ bias, const float* __restrict__ embS,
        const float* __restrict__ x, float* __restrict__ out) {
    int bid = blockIdx.x;                       // 512 = 8 * 64
    int u = (bid & 7) * 64 + (bid >> 3);
    int o0 = (u & 3) * 64;
    int rr = u >> 2;                            // 0..127
    int m0 = (rr & 7) * 128;
    int b  = rr >> 3;
    int wid  = threadIdx.x >> 6;
    int lane = threadIdx.x & 63;
    int wr = (wid >> 1) * 32, wc = (wid & 1) * 64;
    int lr = lane & 15, lg = lane >> 4;

    const f16* A  = wA + (size_t)(o0 + wr + lr) * INNER + lg * 8;
    const f16* Bp = oT + ((size_t)b * HW + m0 + wc + lr) * INNER + lg * 8;

    const f32x4 fzero = {0.f, 0.f, 0.f, 0.f};
    f32x4 acc[2][4];
    #pragma unroll
    for (int i = 0; i < 2; ++i)
        #pragma unroll
        for (int j = 0; j < 4; ++j) acc[i][j] = fzero;

    // K=512 in 16 steps of 32: 8 groups of 2, pinned 1-deep prefetch
    f16x8 afA[2], bfA[4], afB[2], bfB[4];
    auto ld = [&](int k0, f16x8 (&af)[2], f16x8 (&bf)[4]) {
        #pragma unroll
        for (int i = 0; i < 2; ++i)
            af[i] = *reinterpret_cast<const f16x8*>(A + (size_t)i * 16 * INNER + k0);
        #pragma unroll
        for (int j = 0; j < 4; ++j)
            bf[j] = *reinterpret_cast<const f16x8*>(Bp + (size_t)j * 16 * INNER + k0);
    };
    auto mm = [&](const f16x8 (&af)[2], const f16x8 (&bf)[4]) {
        #pragma unroll
        for (int i = 0; i < 2; ++i)
            #pragma unroll
            for (int j = 0; j < 4; ++j)
                acc[i][j] = mfma16(af[i], bf[j], acc[i][j]);
    };
    ld(0, afA, bfA); SB;
    #pragma unroll 1
    for (int g = 0; g < 8; ++g) {
        int k0 = g * 64;
        ld(k0 + 32, afB, bfB); SB;                    // <= 480, always valid
        mm(afA, bfA); SB;
        if (g < 7) { ld(k0 + 64, afA, bfA); } SB;
        mm(afB, bfB); SB;
    }

    #pragma unroll
    for (int i = 0; i < 2; ++i) {
        int ob = o0 + wr + i * 16 + lg * 4;
        #pragma unroll
        for (int j = 0; j < 4; ++j) {
            int m = m0 + wc + j * 16 + lr;
            #pragma unroll
            for (int r = 0; r < 4; ++r) {
                int o = ob + r;
                size_t idx = ((size_t)b * NC + o) * HW + m;
                out[idx] = (acc[i][j][r] + bias[o]) * embS[b * NC + o] + x[idx];
            }
        }
    }
}

extern "C" void kernel_launch(void* const* d_in, const int* in_sizes, int n_in,
                              void* d_out, int out_size, void* d_ws, size_t ws_size,
                              hipStream_t stream) {
    const float* x     = (const float*)d_in[0];
    const float* emb   = (const float*)d_in[1];
    const float* nw    = (const float*)d_in[2];
    const float* nbi   = (const float*)d_in[3];
    const float* in_w  = (const float*)d_in[4];
    const float* in_b  = (const float*)d_in[5];
    const float* out_w = (const float*)d_in[6];
    const float* out_b = (const float*)d_in[7];
    const float* emb_w = (const float*)d_in[8];
    const float* emb_b = (const float*)d_in[9];

    char* p = (char*)d_ws;
    f16* xnT   = (f16*)p;   p += (size_t)NB * HW * NC * 2;        // 8 MB
    f16* w_in  = (f16*)p;   p += (size_t)3 * INNER * NC * 2;      // 768 KB
    f16* w_out = (f16*)p;   p += (size_t)NC * INNER * 2;          // 256 KB
    float* stats = (float*)p; p += (size_t)NB * NG * 2 * 4;       // 4 KB
    float* embS  = (float*)p; p += (size_t)NB * NC * 4;           // 16 KB
    f16* qT = (f16*)p;      p += (size_t)NB * NH * HW * HD * 2;   // 16 MB
    f16* kT = (f16*)p;      p += (size_t)NB * NH * HW * HD * 2;   // 16 MB
    f16* vv = (f16*)p;      p += (size_t)NB * NH * HW * HD * 2;   // 16 MB
    f16* oT = (f16*)p;                                            // 16 MB

    prep_k<<<NB * NG + 512 + 1024, 256, 0, stream>>>(x, stats, in_w, out_w, w_in, w_out,
                                                     emb, emb_w, emb_b, embS);
    gn_apply_k<<<dim3(HW / 32, NB), 256, 0, stream>>>(x, stats, nw, nbi, xnT);
    gemm_qkv_k<<<1536, 256, 0, stream>>>(w_in, xnT, in_b, qT, kT, vv);
    attn_k<<<256, 512, 0, stream>>>(qT, kT, vv, oT);
    gemm_out_k<<<512, 256, 0, stream>>>(w_out, oT, out_b, embS, x, (float*)d_out);
}